// Round 4
// baseline (260.318 us; speedup 1.0000x reference)
//
#include <hip/hip_runtime.h>
#include <hip/hip_cooperative_groups.h>

namespace cg = cooperative_groups;

#define DD 256
#define NROW 2048
#define TROWS 16384   // 8 batches x 2048 rows

typedef __attribute__((ext_vector_type(8))) short short8;
typedef __attribute__((ext_vector_type(4))) float f32x4;

__device__ __forceinline__ unsigned short f2bf(float f) {
  unsigned int u = __float_as_uint(f);
  u += 0x7FFFu + ((u >> 16) & 1u);   // RNE
  return (unsigned short)(u >> 16);
}

__device__ __forceinline__ void gload_lds16(const unsigned short* g, unsigned short* l) {
  __builtin_amdgcn_global_load_lds(
      (const __attribute__((address_space(1))) unsigned int*)(const void*)g,
      (__attribute__((address_space(3))) unsigned int*)(void*)l,
      16, 0, 0);
}

// LDS phase union: max member 72 KB -> 2 blocks/CU (144 KB <= 160 KB)
union SMem {
  struct { float msrow[DD]; float red[DD]; } pr;
  struct { unsigned short As[2][64*32]; unsigned short B1s[2][256*32]; unsigned short B2s[2][256*32]; } fg;
  struct { unsigned short As[2][128*32]; unsigned short Bs[2][128*32]; float q1s[128]; float q2s[128]; } cr;
};

__global__ __launch_bounds__(256, 2)
void k_mega(const float* x1, const float* x2, const float* W,
            const float* bvec, const float* metric,
            unsigned short* Wbf, unsigned short* WpT, float* bp,
            unsigned short* f1M, unsigned short* f2,
            float* qp1, float* qp2, float* out)
{
  __shared__ SMem sm;
  const int tid  = threadIdx.x;
  const int lane = tid & 63;
  const int wave = tid >> 6;
  const int nb   = gridDim.x;

  // ================= phase A: prep (Wbf, WpT, bp) =================
  for (int e = blockIdx.x; e < DD; e += nb) {
    const int d = tid;
    sm.pr.msrow[d] = 0.5f * (metric[e*DD + d] + metric[d*DD + e]);
    Wbf[e*DD + d] = f2bf(W[e*DD + d]);
    __syncthreads();
    float acc = 0.f;
    for (int j = 0; j < DD; ++j) acc += sm.pr.msrow[j] * W[j*DD + d];
    WpT[e*DD + d] = f2bf(acc);
    sm.pr.red[d] = sm.pr.msrow[d] * bvec[d];
    __syncthreads();
    for (int s = 128; s; s >>= 1) { if (d < s) sm.pr.red[d] += sm.pr.red[d + s]; __syncthreads(); }
    if (d == 0) bp[e] = sm.pr.red[0];
    __syncthreads();
  }
  cg::this_grid().sync();

  // ================= phase B: fused convert + dual-B f-GEMM =================
  // u -> row-tile (u>>1)*64, tensor z = u&1. BM=64, BN=256, BK=32.
  {
    const int ar   = tid >> 2;         // A staging row 0..63
    const int ako  = (tid & 3) * 8;    // A staging k-elem offset
    const int lrow = lane >> 2;        // B staging row within 16-chunk
    const int lkk  = (lane & 3) * 8;
    const int lr = lane & 15;
    const int lk = (lane >> 4) * 8;

#define STAGE_B(buf, k0) do { \
  _Pragma("unroll") \
  for (int c = 0; c < 4; ++c) { \
    const int chunk = wave * 4 + c; \
    const int rb = (chunk*16 + lrow)*DD + (k0) + lkk; \
    gload_lds16(Wbf + rb, &sm.fg.B1s[buf][chunk*512]); \
    gload_lds16(WpT + rb, &sm.fg.B2s[buf][chunk*512]); \
  } } while (0)

#define LOAD_A(k0) \
  float4 a0 = *(const float4*)(X + (long long)(row0 + ar)*DD + (k0) + ako); \
  float4 a1 = *(const float4*)(X + (long long)(row0 + ar)*DD + (k0) + ako + 4)

#define CVT_WRITE_A(buf) do { \
  union { unsigned short us[8]; int4 v; } uu; \
  uu.us[0]=f2bf(a0.x); uu.us[1]=f2bf(a0.y); uu.us[2]=f2bf(a0.z); uu.us[3]=f2bf(a0.w); \
  uu.us[4]=f2bf(a1.x); uu.us[5]=f2bf(a1.y); uu.us[6]=f2bf(a1.z); uu.us[7]=f2bf(a1.w); \
  *(int4*)&sm.fg.As[buf][ar*32 + ako] = uu.v; } while (0)

    for (int u = blockIdx.x; u < 512; u += nb) {
      const int row0 = (u >> 1) * 64;
      const int z    = u & 1;
      const float* X       = z ? x2 : x1;
      unsigned short* outp = z ? f2 : f1M;
      float* qp            = z ? qp2 : qp1;

      f32x4 accF[4][4], accM[4][4];
#pragma unroll
      for (int m = 0; m < 4; ++m)
#pragma unroll
        for (int n = 0; n < 4; ++n) { accF[m][n] = (f32x4){0,0,0,0}; accM[m][n] = (f32x4){0,0,0,0}; }

      __syncthreads();   // LDS reuse guard (previous u / phase A)
      { LOAD_A(0); STAGE_B(0, 0); CVT_WRITE_A(0); }
      __syncthreads();

#pragma unroll
      for (int kt = 0; kt < 8; ++kt) {
        const int cur = kt & 1;
        if (kt < 7) {
          const int k0 = (kt + 1) * 32;
          LOAD_A(k0);
          STAGE_B(cur ^ 1, k0);
          short8 af[4];
#pragma unroll
          for (int m = 0; m < 4; ++m) af[m] = *(const short8*)&sm.fg.As[cur][(m*16 + lr)*32 + lk];
#pragma unroll
          for (int n = 0; n < 4; ++n) {
            const short8 b1 = *(const short8*)&sm.fg.B1s[cur][(wave*64 + n*16 + lr)*32 + lk];
            const short8 b2 = *(const short8*)&sm.fg.B2s[cur][(wave*64 + n*16 + lr)*32 + lk];
#pragma unroll
            for (int m = 0; m < 4; ++m) {
              accF[m][n] = __builtin_amdgcn_mfma_f32_16x16x32_bf16(af[m], b1, accF[m][n], 0, 0, 0);
              accM[m][n] = __builtin_amdgcn_mfma_f32_16x16x32_bf16(af[m], b2, accM[m][n], 0, 0, 0);
            }
          }
          CVT_WRITE_A(cur ^ 1);
        } else {
          short8 af[4];
#pragma unroll
          for (int m = 0; m < 4; ++m) af[m] = *(const short8*)&sm.fg.As[cur][(m*16 + lr)*32 + lk];
#pragma unroll
          for (int n = 0; n < 4; ++n) {
            const short8 b1 = *(const short8*)&sm.fg.B1s[cur][(wave*64 + n*16 + lr)*32 + lk];
            const short8 b2 = *(const short8*)&sm.fg.B2s[cur][(wave*64 + n*16 + lr)*32 + lk];
#pragma unroll
            for (int m = 0; m < 4; ++m) {
              accF[m][n] = __builtin_amdgcn_mfma_f32_16x16x32_bf16(af[m], b1, accF[m][n], 0, 0, 0);
              accM[m][n] = __builtin_amdgcn_mfma_f32_16x16x32_bf16(af[m], b2, accM[m][n], 0, 0, 0);
            }
          }
        }
        __syncthreads();
      }

      // epilogue — C/D layout: col = lane&15, row = (lane>>4)*4 + reg
      float bbv[4], bpv4[4];
#pragma unroll
      for (int n = 0; n < 4; ++n) {
        const int coll = wave*64 + n*16 + (lane & 15);
        bbv[n]  = bvec[coll];
        bpv4[n] = bp[coll];
      }
#pragma unroll
      for (int m = 0; m < 4; ++m) {
#pragma unroll
        for (int r = 0; r < 4; ++r) {
          const int rowl = m*16 + (lane >> 4)*4 + r;
          float p = 0.f;
#pragma unroll
          for (int n = 0; n < 4; ++n) {
            const int coll = wave*64 + n*16 + (lane & 15);
            const float fv  = accF[m][n][r] + bbv[n];
            const float fMv = accM[m][n][r] + bpv4[n];
            p += fv * fMv;
            outp[(long long)(row0 + rowl)*DD + coll] = f2bf(z ? fv : fMv);
          }
          p += __shfl_xor(p, 1); p += __shfl_xor(p, 2);
          p += __shfl_xor(p, 4); p += __shfl_xor(p, 8);
          if ((lane & 15) == 0) qp[wave*TROWS + row0 + rowl] = p;
        }
      }
    }
#undef STAGE_B
#undef LOAD_A
#undef CVT_WRITE_A
  }
  cg::this_grid().sync();

  // ================= phase C: batched cross GEMM + similarity =================
  // w -> z = w&7 (XCD-pinned: w&7 == blockIdx&7 since nb % 8 == 0), tile t = w>>3.
  {
    const int wr = wave >> 1;
    const int wc = wave & 1;
    const int lrow = lane >> 2;
    const int lkk  = (lane & 3) * 8;
    const int lr = lane & 15;
    const int lk = (lane >> 4) * 8;

#define STAGE_C(buf, k0) do { \
  _Pragma("unroll") \
  for (int c = 0; c < 2; ++c) { \
    const int chunk = wave * 2 + c; \
    gload_lds16(A + (long long)(row0 + chunk*16 + lrow)*DD + (k0) + lkk, &sm.cr.As[buf][chunk*512]); \
    gload_lds16(B + (long long)(col0 + chunk*16 + lrow)*DD + (k0) + lkk, &sm.cr.Bs[buf][chunk*512]); \
  } } while (0)

    for (int w = blockIdx.x; w < 2048; w += nb) {
      const int z  = w & 7;
      const int t  = w >> 3;
      const int col0 = (t & 15) * 128;
      const int row0 = (t >> 4) * 128;

      const unsigned short* A = f1M + (long long)z * NROW * DD;
      const unsigned short* B = f2  + (long long)z * NROW * DD;

      __syncthreads();   // guard q1s/q2s + LDS reuse from previous tile
      if (tid < 128) {
        const int rg = z*NROW + row0 + tid;
        sm.cr.q1s[tid] = qp1[rg] + qp1[TROWS + rg] + qp1[2*TROWS + rg] + qp1[3*TROWS + rg];
      } else {
        const int cg2 = z*NROW + col0 + (tid - 128);
        sm.cr.q2s[tid-128] = qp2[cg2] + qp2[TROWS + cg2] + qp2[2*TROWS + cg2] + qp2[3*TROWS + cg2];
      }

      f32x4 acc[4][4];
#pragma unroll
      for (int m = 0; m < 4; ++m)
#pragma unroll
        for (int n = 0; n < 4; ++n) acc[m][n] = (f32x4){0,0,0,0};

      STAGE_C(0, 0);
      __syncthreads();

#pragma unroll
      for (int kt = 0; kt < 8; ++kt) {
        const int cur = kt & 1;
        if (kt < 7) STAGE_C(cur ^ 1, (kt + 1) * 32);
        short8 af[4];
#pragma unroll
        for (int m = 0; m < 4; ++m) af[m] = *(const short8*)&sm.cr.As[cur][(wr*64 + m*16 + lr)*32 + lk];
#pragma unroll
        for (int n = 0; n < 4; ++n) {
          const short8 bfr = *(const short8*)&sm.cr.Bs[cur][(wc*64 + n*16 + lr)*32 + lk];
#pragma unroll
          for (int m = 0; m < 4; ++m)
            acc[m][n] = __builtin_amdgcn_mfma_f32_16x16x32_bf16(af[m], bfr, acc[m][n], 0, 0, 0);
        }
        __syncthreads();
      }

      float* outz = out + (long long)z * NROW * NROW;
#pragma unroll
      for (int m = 0; m < 4; ++m) {
#pragma unroll
        for (int r = 0; r < 4; ++r) {
          const int rowl = wr*64 + m*16 + (lane >> 4)*4 + r;
#pragma unroll
          for (int n = 0; n < 4; ++n) {
            const int coll = wc*64 + n*16 + (lane & 15);
            const float dsq = sm.cr.q1s[rowl] + sm.cr.q2s[coll] - 2.0f * acc[m][n][r];
            const float sc = fminf(fmaxf(-dsq, -10.0f), 10.0f);
            outz[(long long)(row0 + rowl)*NROW + (col0 + coll)] = __expf(sc);
          }
        }
      }
    }
#undef STAGE_C
  }
}

extern "C" void kernel_launch(void* const* d_in, const int* in_sizes, int n_in,
                              void* d_out, int out_size, void* d_ws, size_t ws_size,
                              hipStream_t stream) {
  const float* x1     = (const float*)d_in[0];
  const float* x2     = (const float*)d_in[1];
  const float* W      = (const float*)d_in[2];
  const float* bv     = (const float*)d_in[3];
  const float* metric = (const float*)d_in[4];
  float* out = (float*)d_out;

  if (ws_size < 20000000) return;
  unsigned short* p   = (unsigned short*)d_ws;
  unsigned short* f1M = p; p += (size_t)TROWS*DD;
  unsigned short* f2  = p; p += (size_t)TROWS*DD;
  unsigned short* Wbf = p; p += DD*DD;
  unsigned short* WpT = p; p += DD*DD;
  float* fp  = (float*)p;
  float* qp1 = fp; fp += 4*TROWS;
  float* qp2 = fp; fp += 4*TROWS;
  float* bp  = fp; fp += 256;

  int maxb = 0;
  hipOccupancyMaxActiveBlocksPerMultiprocessor(&maxb, k_mega, 256, 0);
  int grid = maxb * 256;          // 256 CUs on MI355X
  if (grid > 512) grid = 512;     // work decomposition max
  if (grid < 8)   grid = 8;       // paranoid fallback (still correct via stride loops)

  void* args[] = { (void*)&x1, (void*)&x2, (void*)&W, (void*)&bv, (void*)&metric,
                   (void*)&Wbf, (void*)&WpT, (void*)&bp,
                   (void*)&f1M, (void*)&f2,
                   (void*)&qp1, (void*)&qp2, (void*)&out };
  hipLaunchCooperativeKernel(k_mega, dim3(grid), dim3(256), args, 0, stream);
}

// Round 5
// 70.312 us; speedup vs baseline: 3.7023x; 3.7023x over previous
//
#include <hip/hip_runtime.h>

#define DD 256
#define NROW 2048
#define TROWS 16384   // 8 batches x 2048 rows

typedef __attribute__((ext_vector_type(8))) short short8;
typedef __attribute__((ext_vector_type(4))) float f32x4;

__device__ __forceinline__ unsigned short f2bf(float f) {
  unsigned int u = __float_as_uint(f);
  u += 0x7FFFu + ((u >> 16) & 1u);   // RNE
  return (unsigned short)(u >> 16);
}

__device__ __forceinline__ void gload_lds16(const unsigned short* g, unsigned short* l) {
  __builtin_amdgcn_global_load_lds(
      (const __attribute__((address_space(1))) unsigned int*)(const void*)g,
      (__attribute__((address_space(3))) unsigned int*)(void*)l,
      16, 0, 0);
}

// LDS bank-conflict swizzle (T2, rule #21 both-sides):
// layout within each 16-row x 32-elem chunk: slot s (16B) of row r holds
// k-group  s ^ ((r>>1)&3).  Writer permutes GLOBAL source (LDS stays linear
// for global_load_lds); reader XORs its k-group with ((r>>1)&3).
// Result: 8 even rows spread over all 4 k-slots -> 2 lanes/bank = free.

// ---------------- prep: Wbf = bf16(W); WpT = Msym@W (bf16); bp = Msym@b ----
__global__ void k_prep(const float* __restrict__ metric, const float* __restrict__ W,
                       const float* __restrict__ bvec,
                       unsigned short* __restrict__ Wbf, unsigned short* __restrict__ WpT,
                       float* __restrict__ bp)
{
  __shared__ float msrow[DD];
  __shared__ float red[DD];
  const int e = blockIdx.x, d = threadIdx.x;
  msrow[d] = 0.5f * (metric[e*DD + d] + metric[d*DD + e]);
  Wbf[e*DD + d] = f2bf(W[e*DD + d]);
  __syncthreads();
  float acc = 0.f;
  for (int j = 0; j < DD; ++j) acc += msrow[j] * W[j*DD + d];
  WpT[e*DD + d] = f2bf(acc);
  red[d] = msrow[d] * bvec[d];
  __syncthreads();
  for (int s = 128; s; s >>= 1) { if (d < s) red[d] += red[d + s]; __syncthreads(); }
  if (d == 0) bp[e] = red[0];
}

// ---------------- fused convert + dual-B f-GEMM ----------------
// BM=64, BN=256, BK=32. z==0: writes f1M; z==1: writes f2. q partials per
// 64-col wave slice.
__global__ __launch_bounds__(256, 2)
void k_fgemm(const float* __restrict__ x1, const float* __restrict__ x2,
             const unsigned short* __restrict__ B1, const unsigned short* __restrict__ B2,
             const float* __restrict__ bb, const float* __restrict__ bpv,
             unsigned short* __restrict__ o1, unsigned short* __restrict__ o2,
             float* __restrict__ qp1, float* __restrict__ qp2)
{
  __shared__ __align__(16) unsigned short As[2][64*32];     //  8 KB
  __shared__ __align__(16) unsigned short B1s[2][256*32];   // 32 KB
  __shared__ __align__(16) unsigned short B2s[2][256*32];   // 32 KB

  const int tid  = threadIdx.x;
  const int lane = tid & 63;
  const int wave = tid >> 6;      // 0..3 = column group (64 cols each)
  const int row0 = blockIdx.x * 64;
  const int z    = blockIdx.y;

  const float* X       = z ? x2 : x1;
  unsigned short* outp = z ? o2 : o1;
  float* qp            = z ? qp2 : qp1;

  f32x4 accF[4][4], accM[4][4];
#pragma unroll
  for (int m = 0; m < 4; ++m)
#pragma unroll
    for (int n = 0; n < 4; ++n) { accF[m][n] = (f32x4){0,0,0,0}; accM[m][n] = (f32x4){0,0,0,0}; }

  // A staging (fp32 -> bf16 regs -> swizzled ds_write)
  const int ar   = tid >> 2;                                  // row 0..63
  const int ako  = (tid & 3) * 8;                             // global k-offset
  const int akos = (((tid & 3) ^ ((ar >> 1) & 3))) * 8;       // swizzled LDS slot
  // B staging (global_load_lds: LDS linear, global source swizzled)
  const int lrow  = lane >> 2;
  const int lkswz = (((lane & 3) ^ ((lrow >> 1) & 3))) * 8;

#define STAGE_B(buf, k0) do { \
  _Pragma("unroll") \
  for (int c = 0; c < 4; ++c) { \
    const int chunk = wave * 4 + c; \
    const int rb = (chunk*16 + lrow)*DD + (k0) + lkswz; \
    gload_lds16(B1 + rb, &B1s[buf][chunk*512]); \
    gload_lds16(B2 + rb, &B2s[buf][chunk*512]); \
  } } while (0)

#define LOAD_A(k0) \
  float4 a0 = *(const float4*)(X + (long long)(row0 + ar)*DD + (k0) + ako); \
  float4 a1 = *(const float4*)(X + (long long)(row0 + ar)*DD + (k0) + ako + 4)

#define CVT_WRITE_A(buf) do { \
  union { unsigned short us[8]; int4 v; } uu; \
  uu.us[0]=f2bf(a0.x); uu.us[1]=f2bf(a0.y); uu.us[2]=f2bf(a0.z); uu.us[3]=f2bf(a0.w); \
  uu.us[4]=f2bf(a1.x); uu.us[5]=f2bf(a1.y); uu.us[6]=f2bf(a1.z); uu.us[7]=f2bf(a1.w); \
  *(int4*)&As[buf][ar*32 + akos] = uu.v; } while (0)

  { LOAD_A(0); STAGE_B(0, 0); CVT_WRITE_A(0); }
  __syncthreads();

  const int lr  = lane & 15;
  const int lks = (((lane >> 4) ^ ((lr >> 1) & 3))) * 8;   // swizzled fragment read

#pragma unroll
  for (int kt = 0; kt < 8; ++kt) {
    const int cur = kt & 1;
    if (kt < 7) {
      const int k0 = (kt + 1) * 32;
      LOAD_A(k0);
      STAGE_B(cur ^ 1, k0);
      short8 af[4];
#pragma unroll
      for (int m = 0; m < 4; ++m) af[m] = *(const short8*)&As[cur][(m*16 + lr)*32 + lks];
#pragma unroll
      for (int n = 0; n < 4; ++n) {
        const short8 b1 = *(const short8*)&B1s[cur][(wave*64 + n*16 + lr)*32 + lks];
        const short8 b2 = *(const short8*)&B2s[cur][(wave*64 + n*16 + lr)*32 + lks];
#pragma unroll
        for (int m = 0; m < 4; ++m) {
          accF[m][n] = __builtin_amdgcn_mfma_f32_16x16x32_bf16(af[m], b1, accF[m][n], 0, 0, 0);
          accM[m][n] = __builtin_amdgcn_mfma_f32_16x16x32_bf16(af[m], b2, accM[m][n], 0, 0, 0);
        }
      }
      CVT_WRITE_A(cur ^ 1);
    } else {
      short8 af[4];
#pragma unroll
      for (int m = 0; m < 4; ++m) af[m] = *(const short8*)&As[cur][(m*16 + lr)*32 + lks];
#pragma unroll
      for (int n = 0; n < 4; ++n) {
        const short8 b1 = *(const short8*)&B1s[cur][(wave*64 + n*16 + lr)*32 + lks];
        const short8 b2 = *(const short8*)&B2s[cur][(wave*64 + n*16 + lr)*32 + lks];
#pragma unroll
        for (int m = 0; m < 4; ++m) {
          accF[m][n] = __builtin_amdgcn_mfma_f32_16x16x32_bf16(af[m], b1, accF[m][n], 0, 0, 0);
          accM[m][n] = __builtin_amdgcn_mfma_f32_16x16x32_bf16(af[m], b2, accM[m][n], 0, 0, 0);
        }
      }
    }
    __syncthreads();
  }

  // epilogue — C/D layout: col = lane&15, row = (lane>>4)*4 + reg
  float bbv[4], bpv4[4];
#pragma unroll
  for (int n = 0; n < 4; ++n) {
    const int coll = wave*64 + n*16 + (lane & 15);
    bbv[n]  = bb[coll];
    bpv4[n] = bpv[coll];
  }
#pragma unroll
  for (int m = 0; m < 4; ++m) {
#pragma unroll
    for (int r = 0; r < 4; ++r) {
      const int rowl = m*16 + (lane >> 4)*4 + r;
      float p = 0.f;
#pragma unroll
      for (int n = 0; n < 4; ++n) {
        const int coll = wave*64 + n*16 + (lane & 15);
        const float fv  = accF[m][n][r] + bbv[n];
        const float fMv = accM[m][n][r] + bpv4[n];
        p += fv * fMv;
        outp[(long long)(row0 + rowl)*DD + coll] = f2bf(z ? fv : fMv);
      }
      p += __shfl_xor(p, 1); p += __shfl_xor(p, 2);
      p += __shfl_xor(p, 4); p += __shfl_xor(p, 8);
      if ((lane & 15) == 0) qp[wave*TROWS + row0 + rowl] = p;
    }
  }
#undef STAGE_B
#undef LOAD_A
#undef CVT_WRITE_A
}

// ---------------- batched cross GEMM + fused similarity epilogue ----------
// 1D grid, z = bid&7 pins each batch to one XCD (bijective: 2048 % 8 == 0).
__global__ __launch_bounds__(256, 2)
void k_cross(const unsigned short* __restrict__ f1M, const unsigned short* __restrict__ f2,
             const float* __restrict__ qp1, const float* __restrict__ qp2,
             float* __restrict__ out)
{
  __shared__ __align__(16) unsigned short As[2][128*32];
  __shared__ __align__(16) unsigned short Bs[2][128*32];
  __shared__ float q1s[128];
  __shared__ float q2s[128];

  const int tid  = threadIdx.x;
  const int lane = tid & 63;
  const int wave = tid >> 6;
  const int wr = wave >> 1;
  const int wc = wave & 1;

  const int bid = blockIdx.x;
  const int z  = bid & 7;
  const int t  = bid >> 3;
  const int bx = t & 15;
  const int by = t >> 4;
  const int row0 = by * 128;
  const int col0 = bx * 128;

  const unsigned short* A = f1M + (long long)z * NROW * DD;
  const unsigned short* B = f2  + (long long)z * NROW * DD;

  if (tid < 128) {
    const int rg = z*NROW + row0 + tid;
    q1s[tid] = qp1[rg] + qp1[TROWS + rg] + qp1[2*TROWS + rg] + qp1[3*TROWS + rg];
  } else {
    const int cg = z*NROW + col0 + (tid - 128);
    q2s[tid-128] = qp2[cg] + qp2[TROWS + cg] + qp2[2*TROWS + cg] + qp2[3*TROWS + cg];
  }

  f32x4 acc[4][4];
#pragma unroll
  for (int m = 0; m < 4; ++m)
#pragma unroll
    for (int n = 0; n < 4; ++n) acc[m][n] = (f32x4){0,0,0,0};

  const int lrow  = lane >> 2;
  const int lkswz = (((lane & 3) ^ ((lrow >> 1) & 3))) * 8;   // swizzled global src

#define STAGE_C(buf, k0) do { \
  _Pragma("unroll") \
  for (int c = 0; c < 2; ++c) { \
    const int chunk = wave * 2 + c; \
    gload_lds16(A + (long long)(row0 + chunk*16 + lrow)*DD + (k0) + lkswz, &As[buf][chunk*512]); \
    gload_lds16(B + (long long)(col0 + chunk*16 + lrow)*DD + (k0) + lkswz, &Bs[buf][chunk*512]); \
  } } while (0)

  STAGE_C(0, 0);
  __syncthreads();

  const int lr  = lane & 15;
  const int lks = (((lane >> 4) ^ ((lr >> 1) & 3))) * 8;      // swizzled read

#pragma unroll
  for (int kt = 0; kt < 8; ++kt) {
    const int cur = kt & 1;
    if (kt < 7) STAGE_C(cur ^ 1, (kt + 1) * 32);
    short8 af[4];
#pragma unroll
    for (int m = 0; m < 4; ++m) af[m] = *(const short8*)&As[cur][(wr*64 + m*16 + lr)*32 + lks];
#pragma unroll
    for (int n = 0; n < 4; ++n) {
      const short8 bfr = *(const short8*)&Bs[cur][(wc*64 + n*16 + lr)*32 + lks];
#pragma unroll
      for (int m = 0; m < 4; ++m)
        acc[m][n] = __builtin_amdgcn_mfma_f32_16x16x32_bf16(af[m], bfr, acc[m][n], 0, 0, 0);
    }
    __syncthreads();
  }

  float* outz = out + (long long)z * NROW * NROW;
#pragma unroll
  for (int m = 0; m < 4; ++m) {
#pragma unroll
    for (int r = 0; r < 4; ++r) {
      const int rowl = wr*64 + m*16 + (lane >> 4)*4 + r;
#pragma unroll
      for (int n = 0; n < 4; ++n) {
        const int coll = wc*64 + n*16 + (lane & 15);
        const float dsq = q1s[rowl] + q2s[coll] - 2.0f * acc[m][n][r];
        const float sc = fminf(fmaxf(-dsq, -10.0f), 10.0f);
        outz[(long long)(row0 + rowl)*NROW + (col0 + coll)] = __expf(sc);
      }
    }
  }
#undef STAGE_C
}

extern "C" void kernel_launch(void* const* d_in, const int* in_sizes, int n_in,
                              void* d_out, int out_size, void* d_ws, size_t ws_size,
                              hipStream_t stream) {
  const float* x1     = (const float*)d_in[0];
  const float* x2     = (const float*)d_in[1];
  const float* W      = (const float*)d_in[2];
  const float* bv     = (const float*)d_in[3];
  const float* metric = (const float*)d_in[4];
  float* out = (float*)d_out;

  if (ws_size < 20000000) return;
  unsigned short* p   = (unsigned short*)d_ws;
  unsigned short* f1M = p; p += (size_t)TROWS*DD;
  unsigned short* f2  = p; p += (size_t)TROWS*DD;
  unsigned short* Wbf = p; p += DD*DD;
  unsigned short* WpT = p; p += DD*DD;
  float* fp  = (float*)p;
  float* qp1 = fp; fp += 4*TROWS;
  float* qp2 = fp; fp += 4*TROWS;
  float* bp  = fp; fp += 256;

  // 1) prep (Wbf, WpT, bp)
  k_prep<<<256, 256, 0, stream>>>(metric, W, bv, Wbf, WpT, bp);
  // 2) fused convert + dual-B GEMM: f1M, f2, q partials
  dim3 gf(256, 2);
  k_fgemm<<<gf, 256, 0, stream>>>(x1, x2, Wbf, WpT, bv, bp, f1M, f2, qp1, qp2);
  // 3) cross GEMM + similarity epilogue (XCD-pinned)
  k_cross<<<2048, 256, 0, stream>>>(f1M, f2, qp1, qp2, out);
}